// Round 1
// baseline (969.340 us; speedup 1.0000x reference)
//
#include <hip/hip_runtime.h>

#define HDIM 512
#define HALF 256
#define NRELS 12
#define NBASES 8
#define NLAYERS 12
#define NBLOCKS 2
#define NHEADS 8
#define NENTS 50000
#define TXTD 768
#define BATCH 32
#define ELEN 50
#define SLEN 128
#define NPOS (BATCH * ELEN)   // 1600

// ---------------------------------------------------------------------------
// 1) Dedupe entity ids -> compact unique list + map[NENTS] (-1 = unused)
// ---------------------------------------------------------------------------
__global__ void dedup_kernel(const int* __restrict__ eid, int* __restrict__ map,
                             int* __restrict__ uniq, int* __restrict__ nuniq) {
    int i = blockIdx.x * blockDim.x + threadIdx.x;
    if (i >= NPOS) return;
    int n = eid[i];
    int old = atomicCAS(&map[n], -1, -2);
    if (old == -1) {
        int idx = atomicAdd(nuniq, 1);
        uniq[idx] = n;
        __threadfence();
        map[n] = idx;
    }
}

// ---------------------------------------------------------------------------
// 2) Edge scan: ballot-select edges whose dst is a needed node; wave-coop
//    float4 gather of x[src] + atomicAdd into agg[u][rel][256], cnt[u][rel]
// ---------------------------------------------------------------------------
__global__ void edge_scatter_kernel(const int* __restrict__ ei, const int* __restrict__ et,
                                    const int* __restrict__ map, const float* __restrict__ x,
                                    float* __restrict__ agg, float* __restrict__ cnt, int E) {
    const int* __restrict__ srcA = ei;
    const int* __restrict__ dstA = ei + E;
    int lane = threadIdx.x & 63;
    int wave = (blockIdx.x * blockDim.x + threadIdx.x) >> 6;
    int nwaves = (gridDim.x * blockDim.x) >> 6;
    for (int base = wave * 64; base < E; base += nwaves * 64) {
        int e = base + lane;
        int c = -1, rel = 0, src = 0;
        if (e < E) {
            int d = dstA[e];
            c = map[d];
            if (c >= 0) { rel = et[e]; src = srcA[e]; }
        }
        unsigned long long m = __ballot(c >= 0);
        while (m) {
            int bit = __builtin_ctzll(m);
            m &= m - 1;
            int cc = __shfl(c, bit);
            int rr = __shfl(rel, bit);
            int ss = __shfl(src, bit);
            float4 v = ((const float4*)(x + (size_t)ss * HALF))[lane];
            float* dest = agg + ((size_t)cc * NRELS + rr) * HALF + lane * 4;
            atomicAdd(dest + 0, v.x);
            atomicAdd(dest + 1, v.y);
            atomicAdd(dest + 2, v.z);
            atomicAdd(dest + 3, v.w);
            if (lane == 0) atomicAdd(&cnt[cc * NRELS + rr], 1.0f);
        }
    }
}

// ---------------------------------------------------------------------------
// 3) Build MBX[u, 2304]: cols [b*256+i] = sum_r comp[r,b]*mean[u,r,i],
//    cols [2048+i] = x[node_u, i]
// ---------------------------------------------------------------------------
__global__ void build_mbx_kernel(const float* __restrict__ agg, const float* __restrict__ cnt,
                                 const int* __restrict__ uniq, const int* __restrict__ nuniq,
                                 const float* __restrict__ comp, const float* __restrict__ x,
                                 float* __restrict__ MBX) {
    int u = blockIdx.x;
    int i = threadIdx.x;  // 256 threads
    __shared__ float sc[NRELS * NBASES];
    if (i < NRELS * NBASES) sc[i] = comp[i];
    __syncthreads();
    float* row = MBX + (size_t)u * (NBASES * HALF + HALF);
    int nu = *nuniq;
    if (u >= nu) {
        for (int b = 0; b < NBASES + 1; ++b) row[b * HALF + i] = 0.f;
        return;
    }
    float mr[NRELS];
    for (int r = 0; r < NRELS; ++r) {
        float c = cnt[u * NRELS + r];
        float inv = 1.f / fmaxf(c, 1.f);
        mr[r] = agg[((size_t)u * NRELS + r) * HALF + i] * inv;
    }
    #pragma unroll
    for (int b = 0; b < NBASES; ++b) {
        float a = 0.f;
        #pragma unroll
        for (int r = 0; r < NRELS; ++r) a += sc[r * NBASES + b] * mr[r];
        row[b * HALF + i] = a;
    }
    row[NBASES * HALF + i] = x[(size_t)uniq[u] * HALF + i];
}

// ---------------------------------------------------------------------------
// 4) Gather text/image raw features for unique nodes
// ---------------------------------------------------------------------------
__global__ void gather_txim_kernel(const int* __restrict__ uniq, const int* __restrict__ nuniq,
                                   const float* __restrict__ txi, const float* __restrict__ imi,
                                   float* __restrict__ TXIN, float* __restrict__ IMIN) {
    int u = blockIdx.x;
    int t = threadIdx.x;
    int nu = *nuniq;
    if (u >= nu) {
        for (int j = t; j < TXTD; j += 256) {
            TXIN[(size_t)u * TXTD + j] = 0.f;
            IMIN[(size_t)u * TXTD + j] = 0.f;
        }
        return;
    }
    int n = uniq[u];
    for (int j = t; j < TXTD; j += 256) {
        TXIN[(size_t)u * TXTD + j] = txi[(size_t)n * TXTD + j];
        IMIN[(size_t)u * TXTD + j] = imi[(size_t)n * TXTD + j];
    }
}

// ---------------------------------------------------------------------------
// 5) q[b] = mean_s(token_embeds[b]) @ cq_w + cq_b
// ---------------------------------------------------------------------------
__global__ void q_kernel(const float* __restrict__ tok, const float* __restrict__ cq_w,
                         const float* __restrict__ cq_b, float* __restrict__ qout) {
    int b = blockIdx.x;
    int t = threadIdx.x;  // 256
    __shared__ float mv[HDIM];
    for (int col = t; col < HDIM; col += 256) {
        float s = 0.f;
        for (int si = 0; si < SLEN; ++si) s += tok[((size_t)b * SLEN + si) * HDIM + col];
        mv[col] = s * (1.0f / SLEN);
    }
    __syncthreads();
    for (int col = t; col < HDIM; col += 256) {
        float acc = cq_b[col];
        for (int i = 0; i < HDIM; ++i) acc += mv[i] * cq_w[(size_t)i * HDIM + col];
        qout[(size_t)b * HDIM + col] = acc;
    }
}

// ---------------------------------------------------------------------------
// 6) qp[z][b] = W_z @ q[b];  ct[z][b] = q[b] . bias_z   (z: 0=kg,1=im,2=tx)
// ---------------------------------------------------------------------------
__global__ void qproj_kernel(const float* __restrict__ q,
                             const float* __restrict__ kgk_w, const float* __restrict__ kgk_b,
                             const float* __restrict__ imk_w, const float* __restrict__ imk_b,
                             const float* __restrict__ txk_w, const float* __restrict__ txk_b,
                             float* __restrict__ qp, float* __restrict__ ct) {
    int b = blockIdx.x, z = blockIdx.y, t = threadIdx.x;
    const float* W = (z == 0) ? kgk_w : ((z == 1) ? imk_w : txk_w);
    const float* bs = (z == 0) ? kgk_b : ((z == 1) ? imk_b : txk_b);
    __shared__ float qv[HDIM];
    qv[t] = q[(size_t)b * HDIM + t];
    qv[t + 256] = q[(size_t)b * HDIM + t + 256];
    __syncthreads();
    for (int i = t; i < HDIM; i += 256) {
        float a = 0.f;
        for (int o = 0; o < HDIM; ++o) a += W[(size_t)i * HDIM + o] * qv[o];
        qp[((size_t)z * BATCH + b) * HDIM + i] = a;
    }
    __shared__ float red[256];
    red[t] = qv[t] * bs[t] + qv[t + 256] * bs[t + 256];
    __syncthreads();
    for (int s = 128; s > 0; s >>= 1) {
        if (t < s) red[t] += red[t + s];
        __syncthreads();
    }
    if (t == 0) ct[z * BATCH + b] = red[0];
}

// ---------------------------------------------------------------------------
// 7) fusion: softmax([kg_s, im_s, tx_s]) weighted mix -> fused[1600, 512]
// ---------------------------------------------------------------------------
__global__ void fusion_kernel(const int* __restrict__ eid, const int* __restrict__ map,
                              const float* __restrict__ KGU, const float* __restrict__ IMU,
                              const float* __restrict__ TXU, const float* __restrict__ qp,
                              const float* __restrict__ ct, float* __restrict__ fused) {
    int bl = blockIdx.x;
    int t = threadIdx.x;  // 256
    int b = bl / ELEN;
    int u = map[eid[bl]];
    const float* kg = KGU + (size_t)u * HDIM;
    const float* im = IMU + (size_t)u * HDIM;
    const float* tx = TXU + (size_t)u * HDIM;
    const float* qkg = qp + ((size_t)0 * BATCH + b) * HDIM;
    const float* qim = qp + ((size_t)1 * BATCH + b) * HDIM;
    const float* qtx = qp + ((size_t)2 * BATCH + b) * HDIM;
    float pkg = 0.f, pim = 0.f, ptx = 0.f;
    for (int e = t; e < HDIM; e += 256) {
        pkg += kg[e] * qkg[e];
        pim += im[e] * qim[e];
        ptx += tx[e] * qtx[e];
    }
    __shared__ float s0[256], s1[256], s2[256];
    s0[t] = pkg; s1[t] = pim; s2[t] = ptx;
    __syncthreads();
    for (int s = 128; s > 0; s >>= 1) {
        if (t < s) { s0[t] += s0[t + s]; s1[t] += s1[t + s]; s2[t] += s2[t + s]; }
        __syncthreads();
    }
    __shared__ float w[3];
    if (t == 0) {
        float a = s0[0] + ct[0 * BATCH + b];
        float c1 = s1[0] + ct[1 * BATCH + b];
        float c2 = s2[0] + ct[2 * BATCH + b];
        float mx = fmaxf(a, fmaxf(c1, c2));
        float ea = __expf(a - mx), eb = __expf(c1 - mx), ec = __expf(c2 - mx);
        float inv = 1.f / (ea + eb + ec);
        w[0] = ea * inv; w[1] = eb * inv; w[2] = ec * inv;
    }
    __syncthreads();
    float w0 = w[0], w1 = w[1], w2 = w[2];
    for (int e = t; e < HDIM; e += 256) {
        fused[(size_t)bl * HDIM + e] = w0 * kg[e] + w1 * im[e] + w2 * tx[e];
    }
}

// ---------------------------------------------------------------------------
// Generic fp32 tiled GEMM: C[M,N] = A[M,K] @ B[K,N] + bias (+relu / +residual)
// SCATTER: write to d_out in [layer, block, B, head, L, hd] layout for pp2.
// ---------------------------------------------------------------------------
template <int BM, int BN, int ACT, bool RES, bool SCATTER>
__global__ __launch_bounds__(256)
void gemm_kernel(const float* __restrict__ A, const float* __restrict__ B,
                 const float* __restrict__ bias, const float* __restrict__ res,
                 float* __restrict__ C, int M, int N, int K) {
    constexpr int BK = 16;
    constexpr int TM = BM / 16;
    constexpr int TN = BN / 16;
    __shared__ float As[BK][BM + 4];
    __shared__ float Bs[BK][BN + 4];
    int tid = threadIdx.x;
    int m0 = blockIdx.y * BM;
    int n0 = blockIdx.x * BN;
    int tx = tid % 16, ty = tid / 16;
    float acc[TM][TN];
    #pragma unroll
    for (int i = 0; i < TM; ++i)
        #pragma unroll
        for (int j = 0; j < TN; ++j) acc[i][j] = 0.f;

    for (int k0 = 0; k0 < K; k0 += BK) {
        #pragma unroll
        for (int p = 0; p < (BM * BK) / 256; ++p) {
            int idx = tid + p * 256;
            int kk = idx % BK;
            int mm = idx / BK;
            int gm = m0 + mm;
            As[kk][mm] = (gm < M) ? A[(size_t)gm * K + k0 + kk] : 0.f;
        }
        #pragma unroll
        for (int p = 0; p < (BN * BK) / (256 * 4); ++p) {
            int idx = tid + p * 256;
            int n4 = idx % (BN / 4);
            int kk = idx / (BN / 4);
            float4 v = *(const float4*)(B + (size_t)(k0 + kk) * N + n0 + n4 * 4);
            *(float4*)(&Bs[kk][n4 * 4]) = v;
        }
        __syncthreads();
        #pragma unroll
        for (int kk = 0; kk < BK; ++kk) {
            float a[TM], bb[TN];
            #pragma unroll
            for (int i = 0; i < TM; ++i) a[i] = As[kk][ty * TM + i];
            #pragma unroll
            for (int j = 0; j < TN; ++j) bb[j] = Bs[kk][tx * TN + j];
            #pragma unroll
            for (int i = 0; i < TM; ++i)
                #pragma unroll
                for (int j = 0; j < TN; ++j) acc[i][j] += a[i] * bb[j];
        }
        __syncthreads();
    }

    #pragma unroll
    for (int i = 0; i < TM; ++i) {
        int gm = m0 + ty * TM + i;
        if (gm >= M) continue;
        #pragma unroll
        for (int j = 0; j < TN; ++j) {
            int gn = n0 + tx * TN + j;
            float v = acc[i][j] + bias[gn];
            if (ACT == 1) v = fmaxf(v, 0.f);
            if (RES) v += res[(size_t)gm * N + gn];
            if (!SCATTER) {
                C[(size_t)gm * N + gn] = v;
            } else {
                int layer = gn >> 10;
                int rem = gn & 1023;
                int blk = rem >> 9;
                int rem2 = rem & 511;
                int head = rem2 >> 6;
                int hd = rem2 & 63;
                int bb_ = gm / ELEN;
                int ll = gm % ELEN;
                size_t oi = (((((size_t)layer * NBLOCKS + blk) * BATCH + bb_) * NHEADS + head) * ELEN + ll) * 64 + hd;
                C[oi] = v;
            }
        }
    }
}

// ---------------------------------------------------------------------------
extern "C" void kernel_launch(void* const* d_in, const int* in_sizes, int n_in,
                              void* d_out, int out_size, void* d_ws, size_t ws_size,
                              hipStream_t stream) {
    const int* entity_ids = (const int*)d_in[0];
    const float* token_embeds = (const float*)d_in[1];
    const int* edge_index = (const int*)d_in[2];
    const int* edge_type = (const int*)d_in[3];
    const float* node_embeds = (const float*)d_in[4];
    const float* rgcn_basis = (const float*)d_in[5];
    const float* rgcn_comp = (const float*)d_in[6];
    const float* rgcn_root = (const float*)d_in[7];
    const float* rgcn_bias = (const float*)d_in[8];
    const float* kg_proj_w = (const float*)d_in[9];
    const float* kg_proj_b = (const float*)d_in[10];
    const float* text_proj_w = (const float*)d_in[11];
    const float* text_proj_b = (const float*)d_in[12];
    const float* image_proj_w = (const float*)d_in[13];
    const float* image_proj_b = (const float*)d_in[14];
    const float* cq_w = (const float*)d_in[15];
    const float* cq_b = (const float*)d_in[16];
    const float* kgk_w = (const float*)d_in[17];
    const float* kgk_b = (const float*)d_in[18];
    const float* imk_w = (const float*)d_in[19];
    const float* imk_b = (const float*)d_in[20];
    const float* txk_w = (const float*)d_in[21];
    const float* txk_b = (const float*)d_in[22];
    const float* pp1_w1 = (const float*)d_in[23];
    const float* pp1_b1 = (const float*)d_in[24];
    const float* pp1_w2 = (const float*)d_in[25];
    const float* pp1_b2 = (const float*)d_in[26];
    const float* pp2_w = (const float*)d_in[27];
    const float* pp2_b = (const float*)d_in[28];
    const float* text_init = (const float*)d_in[29];
    const float* image_init = (const float*)d_in[30];

    const int E = in_sizes[3];  // 500000

    // workspace carve-up (256B aligned)
    size_t off = 0;
    auto alloc = [&](size_t bytes) { size_t o = off; off += (bytes + 255) & ~(size_t)255; return o; };
    char* ws = (char*)d_ws;
    size_t map_o  = alloc((size_t)NENTS * 4);
    size_t nun_o  = alloc(4);
    size_t unq_o  = alloc((size_t)NPOS * 4);
    size_t cnt_o  = alloc((size_t)NPOS * NRELS * 4);
    size_t agg_o  = alloc((size_t)NPOS * NRELS * HALF * 4);
    size_t mbx_o  = alloc((size_t)NPOS * 2304 * 4);
    size_t bb_o   = alloc((size_t)2304 * HALF * 4);
    size_t rg_o   = alloc((size_t)NPOS * HALF * 4);
    size_t kgu_o  = alloc((size_t)NPOS * HDIM * 4);
    size_t txin_o = alloc((size_t)NPOS * TXTD * 4);
    size_t imin_o = alloc((size_t)NPOS * TXTD * 4);
    size_t txu_o  = alloc((size_t)NPOS * HDIM * 4);
    size_t imu_o  = alloc((size_t)NPOS * HDIM * 4);
    size_t q_o    = alloc((size_t)BATCH * HDIM * 4);
    size_t qp_o   = alloc((size_t)3 * BATCH * HDIM * 4);
    size_t ct_o   = alloc((size_t)3 * BATCH * 4);
    size_t fus_o  = alloc((size_t)NPOS * HDIM * 4);
    size_t p1_o   = alloc((size_t)NPOS * HALF * 4);
    size_t h_o    = alloc((size_t)NPOS * HDIM * 4);
    if (off > ws_size) return;  // workspace too small: fail loudly via validation

    int* map = (int*)(ws + map_o);
    int* nuniq = (int*)(ws + nun_o);
    int* uniq = (int*)(ws + unq_o);
    float* cnt = (float*)(ws + cnt_o);
    float* agg = (float*)(ws + agg_o);
    float* MBX = (float*)(ws + mbx_o);
    float* BB  = (float*)(ws + bb_o);
    float* RG  = (float*)(ws + rg_o);
    float* KGU = (float*)(ws + kgu_o);
    float* TXIN = (float*)(ws + txin_o);
    float* IMIN = (float*)(ws + imin_o);
    float* TXU = (float*)(ws + txu_o);
    float* IMU = (float*)(ws + imu_o);
    float* Q   = (float*)(ws + q_o);
    float* QP  = (float*)(ws + qp_o);
    float* CT  = (float*)(ws + ct_o);
    float* FUS = (float*)(ws + fus_o);
    float* P1  = (float*)(ws + p1_o);
    float* Hh  = (float*)(ws + h_o);
    float* OUT = (float*)d_out;

    // init
    hipMemsetAsync(map, 0xFF, (size_t)NENTS * 4, stream);
    hipMemsetAsync(nuniq, 0, 4, stream);
    hipMemsetAsync(agg, 0, (size_t)NPOS * NRELS * HALF * 4, stream);
    hipMemsetAsync(cnt, 0, (size_t)NPOS * NRELS * 4, stream);

    dedup_kernel<<<(NPOS + 255) / 256, 256, 0, stream>>>(entity_ids, map, uniq, nuniq);
    edge_scatter_kernel<<<1024, 256, 0, stream>>>(edge_index, edge_type, map, node_embeds, agg, cnt, E);
    build_mbx_kernel<<<NPOS, 256, 0, stream>>>(agg, cnt, uniq, nuniq, rgcn_comp, node_embeds, MBX);

    // BB = [basis_flat(2048x256); root(256x256)]
    hipMemcpyAsync(BB, rgcn_basis, (size_t)NBASES * HALF * HALF * 4, hipMemcpyDeviceToDevice, stream);
    hipMemcpyAsync(BB + (size_t)NBASES * HALF * HALF, rgcn_root, (size_t)HALF * HALF * 4,
                   hipMemcpyDeviceToDevice, stream);

    gather_txim_kernel<<<NPOS, 256, 0, stream>>>(uniq, nuniq, text_init, image_init, TXIN, IMIN);
    q_kernel<<<BATCH, 256, 0, stream>>>(token_embeds, cq_w, cq_b, Q);
    qproj_kernel<<<dim3(BATCH, 3), 256, 0, stream>>>(Q, kgk_w, kgk_b, imk_w, imk_b, txk_w, txk_b, QP, CT);

    // RG[1600,256] = MBX[1600,2304] @ BB + rgcn_bias
    gemm_kernel<64, 64, 0, false, false><<<dim3(HALF / 64, NPOS / 64), 256, 0, stream>>>(
        MBX, BB, rgcn_bias, nullptr, RG, NPOS, HALF, 2304);
    // KGU = RG @ kg_proj_w + kg_proj_b
    gemm_kernel<64, 64, 0, false, false><<<dim3(HDIM / 64, NPOS / 64), 256, 0, stream>>>(
        RG, kg_proj_w, kg_proj_b, nullptr, KGU, NPOS, HDIM, HALF);
    // TXU = TXIN @ text_proj_w + b ; IMU = IMIN @ image_proj_w + b
    gemm_kernel<64, 64, 0, false, false><<<dim3(HDIM / 64, NPOS / 64), 256, 0, stream>>>(
        TXIN, text_proj_w, text_proj_b, nullptr, TXU, NPOS, HDIM, TXTD);
    gemm_kernel<64, 64, 0, false, false><<<dim3(HDIM / 64, NPOS / 64), 256, 0, stream>>>(
        IMIN, image_proj_w, image_proj_b, nullptr, IMU, NPOS, HDIM, TXTD);

    fusion_kernel<<<NPOS, 256, 0, stream>>>(entity_ids, map, KGU, IMU, TXU, QP, CT, FUS);

    // P1 = relu(FUS @ pp1_w1 + pp1_b1)
    gemm_kernel<64, 64, 1, false, false><<<dim3(HALF / 64, NPOS / 64), 256, 0, stream>>>(
        FUS, pp1_w1, pp1_b1, nullptr, P1, NPOS, HALF, HDIM);
    // H = P1 @ pp1_w2 + pp1_b2 + FUS
    gemm_kernel<64, 64, 0, true, false><<<dim3(HDIM / 64, NPOS / 64), 256, 0, stream>>>(
        P1, pp1_w2, pp1_b2, FUS, Hh, NPOS, HDIM, HALF);
    // OUT = scatter(H @ pp2_w + pp2_b)
    gemm_kernel<128, 128, 0, false, true><<<dim3(12288 / 128, (NPOS + 127) / 128), 256, 0, stream>>>(
        Hh, pp2_w, pp2_b, nullptr, OUT, NPOS, 12288, HALF * 2);

    // loss_cl = 0.0f (last element of concatenated tuple output)
    hipMemsetAsync((char*)d_out + (size_t)19660800 * 4, 0, 4, stream);
}

// Round 2
// 334.532 us; speedup vs baseline: 2.8976x; 2.8976x over previous
//
#include <hip/hip_runtime.h>

#define HDIM 512
#define HALF 256
#define NRELS 12
#define NBASES 8
#define NLAYERS 12
#define NBLOCKS 2
#define NHEADS 8
#define NENTS 50000
#define TXTD 768
#define BATCH 32
#define ELEN 50
#define SLEN 128
#define NPOS (BATCH * ELEN)   // 1600

typedef unsigned short u16;
typedef __attribute__((ext_vector_type(8))) __bf16 bf16x8;
typedef __attribute__((ext_vector_type(4))) float f32x4;

__device__ __forceinline__ u16 f2bf(float f) {
    unsigned int u = __float_as_uint(f);
    unsigned int r = (u + 0x7FFFu + ((u >> 16) & 1u)) >> 16;
    return (u16)r;
}
__device__ __forceinline__ float bf2f(u16 v) {
    return __uint_as_float(((unsigned int)v) << 16);
}

#define ASYNC_COPY16(g, l)                                                              \
    __builtin_amdgcn_global_load_lds((const __attribute__((address_space(1))) void*)(g), \
                                     (__attribute__((address_space(3))) unsigned int*)(l), 16, 0, 0)

// ---------------------------------------------------------------------------
// 1) Dedupe entity ids -> compact unique list + map[NENTS] (-1 = unused)
// ---------------------------------------------------------------------------
__global__ void dedup_kernel(const int* __restrict__ eid, int* __restrict__ map,
                             int* __restrict__ uniq, int* __restrict__ nuniq) {
    int i = blockIdx.x * blockDim.x + threadIdx.x;
    if (i >= NPOS) return;
    int n = eid[i];
    int old = atomicCAS(&map[n], -1, -2);
    if (old == -1) {
        int idx = atomicAdd(nuniq, 1);
        uniq[idx] = n;
        __threadfence();
        map[n] = idx;
    }
}

// ---------------------------------------------------------------------------
// 2) Edge scan: ballot-select edges whose dst is a needed node
// ---------------------------------------------------------------------------
__global__ void edge_scatter_kernel(const int* __restrict__ ei, const int* __restrict__ et,
                                    const int* __restrict__ map, const float* __restrict__ x,
                                    float* __restrict__ agg, float* __restrict__ cnt, int E) {
    const int* __restrict__ srcA = ei;
    const int* __restrict__ dstA = ei + E;
    int lane = threadIdx.x & 63;
    int wave = (blockIdx.x * blockDim.x + threadIdx.x) >> 6;
    int nwaves = (gridDim.x * blockDim.x) >> 6;
    for (int base = wave * 64; base < E; base += nwaves * 64) {
        int e = base + lane;
        int c = -1, rel = 0, src = 0;
        if (e < E) {
            int d = dstA[e];
            c = map[d];
            if (c >= 0) { rel = et[e]; src = srcA[e]; }
        }
        unsigned long long m = __ballot(c >= 0);
        while (m) {
            int bit = __builtin_ctzll(m);
            m &= m - 1;
            int cc = __shfl(c, bit);
            int rr = __shfl(rel, bit);
            int ss = __shfl(src, bit);
            float4 v = ((const float4*)(x + (size_t)ss * HALF))[lane];
            float* dest = agg + ((size_t)cc * NRELS + rr) * HALF + lane * 4;
            atomicAdd(dest + 0, v.x);
            atomicAdd(dest + 1, v.y);
            atomicAdd(dest + 2, v.z);
            atomicAdd(dest + 3, v.w);
            if (lane == 0) atomicAdd(&cnt[cc * NRELS + rr], 1.0f);
        }
    }
}

// ---------------------------------------------------------------------------
// 3) Build MBX[u, 2304] bf16: cols [b*256+i] = sum_r comp[r,b]*mean[u,r,i],
//    cols [2048+i] = x[node_u, i]
// ---------------------------------------------------------------------------
__global__ void build_mbx_kernel(const float* __restrict__ agg, const float* __restrict__ cnt,
                                 const int* __restrict__ uniq, const int* __restrict__ nuniq,
                                 const float* __restrict__ comp, const float* __restrict__ x,
                                 u16* __restrict__ MBX) {
    int u = blockIdx.x;
    int i = threadIdx.x;  // 256 threads
    __shared__ float sc[NRELS * NBASES];
    if (i < NRELS * NBASES) sc[i] = comp[i];
    __syncthreads();
    u16* row = MBX + (size_t)u * (NBASES * HALF + HALF);
    int nu = *nuniq;
    if (u >= nu) {
        for (int b = 0; b < NBASES + 1; ++b) row[b * HALF + i] = 0;
        return;
    }
    float mr[NRELS];
    for (int r = 0; r < NRELS; ++r) {
        float c = cnt[u * NRELS + r];
        float inv = 1.f / fmaxf(c, 1.f);
        mr[r] = agg[((size_t)u * NRELS + r) * HALF + i] * inv;
    }
    #pragma unroll
    for (int b = 0; b < NBASES; ++b) {
        float a = 0.f;
        #pragma unroll
        for (int r = 0; r < NRELS; ++r) a += sc[r * NBASES + b] * mr[r];
        row[b * HALF + i] = f2bf(a);
    }
    row[NBASES * HALF + i] = f2bf(x[(size_t)uniq[u] * HALF + i]);
}

// ---------------------------------------------------------------------------
// 4) Gather text/image raw features for unique nodes -> bf16
// ---------------------------------------------------------------------------
__global__ void gather_txim_kernel(const int* __restrict__ uniq, const int* __restrict__ nuniq,
                                   const float* __restrict__ txi, const float* __restrict__ imi,
                                   u16* __restrict__ TXIN, u16* __restrict__ IMIN) {
    int u = blockIdx.x;
    int t = threadIdx.x;
    int nu = *nuniq;
    if (u >= nu) {
        for (int j = t; j < TXTD; j += 256) {
            TXIN[(size_t)u * TXTD + j] = 0;
            IMIN[(size_t)u * TXTD + j] = 0;
        }
        return;
    }
    int n = uniq[u];
    for (int j = t; j < TXTD; j += 256) {
        TXIN[(size_t)u * TXTD + j] = f2bf(txi[(size_t)n * TXTD + j]);
        IMIN[(size_t)u * TXTD + j] = f2bf(imi[(size_t)n * TXTD + j]);
    }
}

// ---------------------------------------------------------------------------
// 5) q[b] = mean_s(token_embeds[b]) @ cq_w + cq_b  (fp32 + bf16 copies)
// ---------------------------------------------------------------------------
__global__ void q_kernel(const float* __restrict__ tok, const float* __restrict__ cq_w,
                         const float* __restrict__ cq_b, float* __restrict__ qout,
                         u16* __restrict__ qbf) {
    int b = blockIdx.x;
    int t = threadIdx.x;  // 256
    __shared__ float mv[HDIM];
    for (int col = t; col < HDIM; col += 256) {
        float s = 0.f;
        for (int si = 0; si < SLEN; ++si) s += tok[((size_t)b * SLEN + si) * HDIM + col];
        mv[col] = s * (1.0f / SLEN);
    }
    __syncthreads();
    for (int col = t; col < HDIM; col += 256) {
        float acc = cq_b[col];
        for (int i = 0; i < HDIM; ++i) acc += mv[i] * cq_w[(size_t)i * HDIM + col];
        qout[(size_t)b * HDIM + col] = acc;
        qbf[(size_t)b * HDIM + col] = f2bf(acc);
    }
}

// ---------------------------------------------------------------------------
// 6) ct[z][b] = q[b] . bias_z
// ---------------------------------------------------------------------------
__global__ void ct_kernel(const float* __restrict__ Q, const float* __restrict__ kgk_b,
                          const float* __restrict__ imk_b, const float* __restrict__ txk_b,
                          float* __restrict__ CT) {
    int z = blockIdx.x;
    int lane = threadIdx.x & 63;
    int wv = threadIdx.x >> 6;
    const float* bz = (z == 0) ? kgk_b : ((z == 1) ? imk_b : txk_b);
    for (int b = wv; b < BATCH; b += 4) {
        float s = 0.f;
        for (int o = lane; o < HDIM; o += 64) s += Q[(size_t)b * HDIM + o] * bz[o];
        for (int off = 32; off; off >>= 1) s += __shfl_down(s, off);
        if (lane == 0) CT[z * BATCH + b] = s;
    }
}

// ---------------------------------------------------------------------------
// 7) fusion: softmax scores -> fused (bf16 for GEMM-A + fp32 for residual)
// ---------------------------------------------------------------------------
__global__ void fusion_kernel(const int* __restrict__ eid, const int* __restrict__ map,
                              const u16* __restrict__ KGU, const u16* __restrict__ IMU,
                              const u16* __restrict__ TXU, const float* __restrict__ qp,
                              const float* __restrict__ ct, u16* __restrict__ fusedb,
                              float* __restrict__ fusedf) {
    int bl = blockIdx.x;
    int t = threadIdx.x;  // 256
    int b = bl / ELEN;
    int u = map[eid[bl]];
    const u16* kg = KGU + (size_t)u * HDIM;
    const u16* im = IMU + (size_t)u * HDIM;
    const u16* tx = TXU + (size_t)u * HDIM;
    const float* qkg = qp + ((size_t)0 * BATCH + b) * HDIM;
    const float* qim = qp + ((size_t)1 * BATCH + b) * HDIM;
    const float* qtx = qp + ((size_t)2 * BATCH + b) * HDIM;
    float pkg = 0.f, pim = 0.f, ptx = 0.f;
    for (int e = t; e < HDIM; e += 256) {
        pkg += bf2f(kg[e]) * qkg[e];
        pim += bf2f(im[e]) * qim[e];
        ptx += bf2f(tx[e]) * qtx[e];
    }
    __shared__ float s0[256], s1[256], s2[256];
    s0[t] = pkg; s1[t] = pim; s2[t] = ptx;
    __syncthreads();
    for (int s = 128; s > 0; s >>= 1) {
        if (t < s) { s0[t] += s0[t + s]; s1[t] += s1[t + s]; s2[t] += s2[t + s]; }
        __syncthreads();
    }
    __shared__ float w[3];
    if (t == 0) {
        float a = s0[0] + ct[0 * BATCH + b];
        float c1 = s1[0] + ct[1 * BATCH + b];
        float c2 = s2[0] + ct[2 * BATCH + b];
        float mx = fmaxf(a, fmaxf(c1, c2));
        float ea = __expf(a - mx), eb = __expf(c1 - mx), ec = __expf(c2 - mx);
        float inv = 1.f / (ea + eb + ec);
        w[0] = ea * inv; w[1] = eb * inv; w[2] = ec * inv;
    }
    __syncthreads();
    float w0 = w[0], w1 = w[1], w2 = w[2];
    for (int e = t; e < HDIM; e += 256) {
        float v = w0 * bf2f(kg[e]) + w1 * bf2f(im[e]) + w2 * bf2f(tx[e]);
        fusedf[(size_t)bl * HDIM + e] = v;
        fusedb[(size_t)bl * HDIM + e] = f2bf(v);
    }
}

// ---------------------------------------------------------------------------
// fp32 [K][N] -> bf16 [N][koff+k] transpose-convert (32x32 tiles)
// ---------------------------------------------------------------------------
__global__ void transpose_conv_kernel(const float* __restrict__ W, u16* __restrict__ WT,
                                      int K, int N, int ldt, int koff) {
    __shared__ u16 t[32][33];
    int n0 = blockIdx.x * 32, k0 = blockIdx.y * 32;
    int tx = threadIdx.x & 31, ty = threadIdx.x >> 5;  // 32 x 8
    for (int i = ty; i < 32; i += 8)
        t[i][tx] = f2bf(W[(size_t)(k0 + i) * N + n0 + tx]);
    __syncthreads();
    for (int i = ty; i < 32; i += 8)
        WT[(size_t)(n0 + i) * ldt + koff + k0 + tx] = t[tx][i];
}

// fp32 -> bf16 straight convert (n multiple of 4)
__global__ void conv_bf16_kernel(const float* __restrict__ W, u16* __restrict__ O, int n4) {
    int i = blockIdx.x * blockDim.x + threadIdx.x;
    if (i >= n4) return;
    float4 v = ((const float4*)W)[i];
    ushort4 o;
    o.x = f2bf(v.x); o.y = f2bf(v.y); o.z = f2bf(v.z); o.w = f2bf(v.w);
    ((ushort4*)O)[i] = o;
}

// ---------------------------------------------------------------------------
// MFMA bf16 GEMM: C[M,N] = A[M,K](bf16) @ BT[N,K](bf16)^T + bias
// BK=64, global_load_lds w/ pre-swizzled source, XOR-swizzled ds_read_b128.
// ---------------------------------------------------------------------------
template <int BM, int BN, int WM, int WN, int ACT, bool RES, bool SCATTER, bool OUTBF>
__global__ __launch_bounds__(256)
void mfma_gemm(const u16* __restrict__ A, const u16* __restrict__ BT,
               const float* __restrict__ bias, const float* __restrict__ res,
               void* __restrict__ Cout, int M, int N, int K) {
    constexpr int MF = WM / 16, NF = WN / 16;
    constexpr int NWC = BN / WN;
    __shared__ u16 ldsA[BM][64];
    __shared__ u16 ldsB[BN][64];
    const int tid = threadIdx.x;
    const int lane = tid & 63;
    const int wv = tid >> 6;
    const int m0 = blockIdx.y * BM;
    const int n0 = blockIdx.x * BN;
    const int wr = wv / NWC, wc = wv % NWC;
    const int srow = lane >> 3;   // 0..7 within 8-row chunk
    const int sslot = lane & 7;   // 16B slot within 128B row

    f32x4 acc[MF][NF];
    #pragma unroll
    for (int i = 0; i < MF; ++i)
        #pragma unroll
        for (int j = 0; j < NF; ++j)
            #pragma unroll
            for (int r = 0; r < 4; ++r) acc[i][j][r] = 0.f;

    for (int k0 = 0; k0 < K; k0 += 64) {
        #pragma unroll
        for (int i = 0; i < BM / 32; ++i) {
            int R = wv * (BM / 4) + i * 8 + srow;
            int gm = m0 + R;
            gm = gm < M ? gm : M - 1;
            int s = sslot ^ (R & 7);
            ASYNC_COPY16(A + (size_t)gm * K + k0 + s * 8, &ldsA[wv * (BM / 4) + i * 8][0]);
        }
        #pragma unroll
        for (int i = 0; i < BN / 32; ++i) {
            int R = wv * (BN / 4) + i * 8 + srow;
            int s = sslot ^ (R & 7);
            ASYNC_COPY16(BT + (size_t)(n0 + R) * K + k0 + s * 8, &ldsB[wv * (BN / 4) + i * 8][0]);
        }
        __syncthreads();
        #pragma unroll
        for (int ks = 0; ks < 2; ++ks) {
            bf16x8 af[MF], bf[NF];
            int kg = ks * 4 + (lane >> 4);
            int rl = lane & 15;
            #pragma unroll
            for (int i = 0; i < MF; ++i) {
                int row = wr * WM + i * 16 + rl;
                af[i] = *(const bf16x8*)&ldsA[row][(kg ^ (row & 7)) * 8];
            }
            #pragma unroll
            for (int j = 0; j < NF; ++j) {
                int row = wc * WN + j * 16 + rl;
                bf[j] = *(const bf16x8*)&ldsB[row][(kg ^ (row & 7)) * 8];
            }
            #pragma unroll
            for (int i = 0; i < MF; ++i)
                #pragma unroll
                for (int j = 0; j < NF; ++j)
                    acc[i][j] = __builtin_amdgcn_mfma_f32_16x16x32_bf16(af[i], bf[j], acc[i][j], 0, 0, 0);
        }
        __syncthreads();
    }

    // epilogue: C/D layout col=lane&15, row=(lane>>4)*4+reg  [m89]
    const int rl = lane & 15, rg = lane >> 4;
    #pragma unroll
    for (int i = 0; i < MF; ++i) {
        #pragma unroll
        for (int j = 0; j < NF; ++j) {
            int col = n0 + wc * WN + j * 16 + rl;
            float bv = bias[col];
            #pragma unroll
            for (int r = 0; r < 4; ++r) {
                int row = m0 + wr * WM + i * 16 + rg * 4 + r;
                if (row >= M) continue;
                float x = acc[i][j][r] + bv;
                if (ACT == 1) x = fmaxf(x, 0.f);
                if (RES) x += res[(size_t)row * N + col];
                if (SCATTER) {
                    int layer = col >> 10, blk = (col >> 9) & 1, head = (col >> 6) & 7, hd = col & 63;
                    int bb = row / ELEN, ll = row - bb * ELEN;
                    size_t oi = (((((size_t)layer * NBLOCKS + blk) * BATCH + bb) * NHEADS + head) * ELEN + ll) * 64 + hd;
                    ((float*)Cout)[oi] = x;
                } else if (OUTBF) {
                    ((u16*)Cout)[(size_t)row * N + col] = f2bf(x);
                } else {
                    ((float*)Cout)[(size_t)row * N + col] = x;
                }
            }
        }
    }
}

// ---------------------------------------------------------------------------
extern "C" void kernel_launch(void* const* d_in, const int* in_sizes, int n_in,
                              void* d_out, int out_size, void* d_ws, size_t ws_size,
                              hipStream_t stream) {
    const int* entity_ids = (const int*)d_in[0];
    const float* token_embeds = (const float*)d_in[1];
    const int* edge_index = (const int*)d_in[2];
    const int* edge_type = (const int*)d_in[3];
    const float* node_embeds = (const float*)d_in[4];
    const float* rgcn_basis = (const float*)d_in[5];
    const float* rgcn_comp = (const float*)d_in[6];
    const float* rgcn_root = (const float*)d_in[7];
    const float* rgcn_bias = (const float*)d_in[8];
    const float* kg_proj_w = (const float*)d_in[9];
    const float* kg_proj_b = (const float*)d_in[10];
    const float* text_proj_w = (const float*)d_in[11];
    const float* text_proj_b = (const float*)d_in[12];
    const float* image_proj_w = (const float*)d_in[13];
    const float* image_proj_b = (const float*)d_in[14];
    const float* cq_w = (const float*)d_in[15];
    const float* cq_b = (const float*)d_in[16];
    const float* kgk_w = (const float*)d_in[17];
    // kgk_b = d_in[18]
    const float* imk_w = (const float*)d_in[19];
    // imk_b = d_in[20]
    const float* txk_w = (const float*)d_in[21];
    // txk_b = d_in[22]
    const float* pp1_w1 = (const float*)d_in[23];
    const float* pp1_b1 = (const float*)d_in[24];
    const float* pp1_w2 = (const float*)d_in[25];
    const float* pp1_b2 = (const float*)d_in[26];
    const float* pp2_w = (const float*)d_in[27];
    const float* pp2_b = (const float*)d_in[28];
    const float* text_init = (const float*)d_in[29];
    const float* image_init = (const float*)d_in[30];

    const int E = in_sizes[3];  // 500000

    size_t off = 0;
    auto alloc = [&](size_t bytes) { size_t o = off; off += (bytes + 255) & ~(size_t)255; return o; };
    char* ws = (char*)d_ws;
    size_t map_o  = alloc((size_t)NENTS * 4);
    size_t nun_o  = alloc(4);
    size_t unq_o  = alloc((size_t)NPOS * 4);
    size_t cnt_o  = alloc((size_t)NPOS * NRELS * 4);
    size_t agg_o  = alloc((size_t)NPOS * NRELS * HALF * 4);   // 19.66MB; pp2T aliases this later
    size_t mbx_o  = alloc((size_t)NPOS * 2304 * 2);
    size_t bbt_o  = alloc((size_t)HALF * 2304 * 2);
    size_t rg_o   = alloc((size_t)NPOS * HALF * 2);
    size_t kgt_o  = alloc((size_t)HDIM * HALF * 2);
    size_t kgu_o  = alloc((size_t)NPOS * HDIM * 2);
    size_t txin_o = alloc((size_t)NPOS * TXTD * 2);
    size_t imin_o = alloc((size_t)NPOS * TXTD * 2);
    size_t txt_o  = alloc((size_t)HDIM * TXTD * 2);
    size_t imt_o  = alloc((size_t)HDIM * TXTD * 2);
    size_t txu_o  = alloc((size_t)NPOS * HDIM * 2);
    size_t imu_o  = alloc((size_t)NPOS * HDIM * 2);
    size_t q_o    = alloc((size_t)BATCH * HDIM * 4);
    size_t qb_o   = alloc((size_t)BATCH * HDIM * 2);
    size_t kgw_o  = alloc((size_t)HDIM * HDIM * 2);
    size_t imw_o  = alloc((size_t)HDIM * HDIM * 2);
    size_t txw_o  = alloc((size_t)HDIM * HDIM * 2);
    size_t qp_o   = alloc((size_t)3 * BATCH * HDIM * 4);
    size_t ct_o   = alloc((size_t)3 * BATCH * 4);
    size_t zb_o   = alloc((size_t)HDIM * 4);
    size_t fub_o  = alloc((size_t)NPOS * HDIM * 2);
    size_t fuf_o  = alloc((size_t)NPOS * HDIM * 4);
    size_t p1_o   = alloc((size_t)NPOS * HALF * 2);
    size_t w1t_o  = alloc((size_t)HALF * HDIM * 2);
    size_t w2t_o  = alloc((size_t)HDIM * HALF * 2);
    size_t h_o    = alloc((size_t)NPOS * HDIM * 2);
    if (off > ws_size) return;

    int* map = (int*)(ws + map_o);
    int* nuniq = (int*)(ws + nun_o);
    int* uniq = (int*)(ws + unq_o);
    float* cnt = (float*)(ws + cnt_o);
    float* agg = (float*)(ws + agg_o);
    u16* MBX = (u16*)(ws + mbx_o);
    u16* BBT = (u16*)(ws + bbt_o);
    u16* RG  = (u16*)(ws + rg_o);
    u16* KGT = (u16*)(ws + kgt_o);
    u16* KGU = (u16*)(ws + kgu_o);
    u16* TXIN = (u16*)(ws + txin_o);
    u16* IMIN = (u16*)(ws + imin_o);
    u16* TXT = (u16*)(ws + txt_o);
    u16* IMT = (u16*)(ws + imt_o);
    u16* TXU = (u16*)(ws + txu_o);
    u16* IMU = (u16*)(ws + imu_o);
    float* Q   = (float*)(ws + q_o);
    u16* QB  = (u16*)(ws + qb_o);
    u16* KGW = (u16*)(ws + kgw_o);
    u16* IMW = (u16*)(ws + imw_o);
    u16* TXW = (u16*)(ws + txw_o);
    float* QP  = (float*)(ws + qp_o);
    float* CT  = (float*)(ws + ct_o);
    float* ZB  = (float*)(ws + zb_o);
    u16* FUB = (u16*)(ws + fub_o);
    float* FUF = (float*)(ws + fuf_o);
    u16* P1  = (u16*)(ws + p1_o);
    u16* W1T = (u16*)(ws + w1t_o);
    u16* W2T = (u16*)(ws + w2t_o);
    u16* Hh  = (u16*)(ws + h_o);
    u16* PP2T = (u16*)(ws + agg_o);  // alias: agg is dead after build_mbx
    float* OUT = (float*)d_out;

    hipMemsetAsync(map, 0xFF, (size_t)NENTS * 4, stream);
    hipMemsetAsync(nuniq, 0, 4, stream);
    hipMemsetAsync(agg, 0, (size_t)NPOS * NRELS * HALF * 4, stream);
    hipMemsetAsync(cnt, 0, (size_t)NPOS * NRELS * 4, stream);
    hipMemsetAsync(ZB, 0, (size_t)HDIM * 4, stream);

    dedup_kernel<<<(NPOS + 255) / 256, 256, 0, stream>>>(entity_ids, map, uniq, nuniq);
    edge_scatter_kernel<<<1024, 256, 0, stream>>>(edge_index, edge_type, map, node_embeds, agg, cnt, E);
    build_mbx_kernel<<<NPOS, 256, 0, stream>>>(agg, cnt, uniq, nuniq, rgcn_comp, node_embeds, MBX);

    // weight preprocessing (bf16):  BT layout = [N][K]
    transpose_conv_kernel<<<dim3(HALF / 32, 2048 / 32), 256, 0, stream>>>(rgcn_basis, BBT, 2048, HALF, 2304, 0);
    transpose_conv_kernel<<<dim3(HALF / 32, HALF / 32), 256, 0, stream>>>(rgcn_root, BBT, HALF, HALF, 2304, 2048);
    transpose_conv_kernel<<<dim3(HDIM / 32, HALF / 32), 256, 0, stream>>>(kg_proj_w, KGT, HALF, HDIM, HALF, 0);
    transpose_conv_kernel<<<dim3(HDIM / 32, TXTD / 32), 256, 0, stream>>>(text_proj_w, TXT, TXTD, HDIM, TXTD, 0);
    transpose_conv_kernel<<<dim3(HDIM / 32, TXTD / 32), 256, 0, stream>>>(image_proj_w, IMT, TXTD, HDIM, TXTD, 0);
    transpose_conv_kernel<<<dim3(HALF / 32, HDIM / 32), 256, 0, stream>>>(pp1_w1, W1T, HDIM, HALF, HDIM, 0);
    transpose_conv_kernel<<<dim3(HDIM / 32, HALF / 32), 256, 0, stream>>>(pp1_w2, W2T, HALF, HDIM, HALF, 0);
    transpose_conv_kernel<<<dim3(12288 / 32, HDIM / 32), 256, 0, stream>>>(pp2_w, PP2T, HDIM, 12288, HDIM, 0);
    // score weights used as [N][K] directly (no transpose needed)
    conv_bf16_kernel<<<(HDIM * HDIM / 4 + 255) / 256, 256, 0, stream>>>(kgk_w, KGW, HDIM * HDIM / 4);
    conv_bf16_kernel<<<(HDIM * HDIM / 4 + 255) / 256, 256, 0, stream>>>(imk_w, IMW, HDIM * HDIM / 4);
    conv_bf16_kernel<<<(HDIM * HDIM / 4 + 255) / 256, 256, 0, stream>>>(txk_w, TXW, HDIM * HDIM / 4);

    gather_txim_kernel<<<NPOS, 256, 0, stream>>>(uniq, nuniq, text_init, image_init, TXIN, IMIN);
    q_kernel<<<BATCH, 256, 0, stream>>>(token_embeds, cq_w, cq_b, Q, QB);
    ct_kernel<<<3, 256, 0, stream>>>(Q, (const float*)d_in[18], (const float*)d_in[20],
                                     (const float*)d_in[22], CT);

    // QP[z] = Q @ Wz^T  (M=32 padded into one 64-tile)
    mfma_gemm<64, 64, 32, 32, 0, false, false, false><<<dim3(8, 1), 256, 0, stream>>>(
        QB, KGW, ZB, nullptr, QP + 0 * BATCH * HDIM, BATCH, HDIM, HDIM);
    mfma_gemm<64, 64, 32, 32, 0, false, false, false><<<dim3(8, 1), 256, 0, stream>>>(
        QB, IMW, ZB, nullptr, QP + 1 * BATCH * HDIM, BATCH, HDIM, HDIM);
    mfma_gemm<64, 64, 32, 32, 0, false, false, false><<<dim3(8, 1), 256, 0, stream>>>(
        QB, TXW, ZB, nullptr, QP + 2 * BATCH * HDIM, BATCH, HDIM, HDIM);

    // RG = MBX @ BBT^T + rgcn_bias
    mfma_gemm<64, 64, 32, 32, 0, false, false, true><<<dim3(HALF / 64, NPOS / 64), 256, 0, stream>>>(
        MBX, BBT, rgcn_bias, nullptr, RG, NPOS, HALF, 2304);
    // KGU = RG @ kg_proj + b
    mfma_gemm<64, 64, 32, 32, 0, false, false, true><<<dim3(HDIM / 64, NPOS / 64), 256, 0, stream>>>(
        RG, KGT, kg_proj_b, nullptr, KGU, NPOS, HDIM, HALF);
    // TXU / IMU
    mfma_gemm<64, 64, 32, 32, 0, false, false, true><<<dim3(HDIM / 64, NPOS / 64), 256, 0, stream>>>(
        TXIN, TXT, text_proj_b, nullptr, TXU, NPOS, HDIM, TXTD);
    mfma_gemm<64, 64, 32, 32, 0, false, false, true><<<dim3(HDIM / 64, NPOS / 64), 256, 0, stream>>>(
        IMIN, IMT, image_proj_b, nullptr, IMU, NPOS, HDIM, TXTD);

    fusion_kernel<<<NPOS, 256, 0, stream>>>(entity_ids, map, KGU, IMU, TXU, QP, CT, FUB, FUF);

    // P1 = relu(FUS @ pp1_w1 + b1)
    mfma_gemm<64, 64, 32, 32, 1, false, false, true><<<dim3(HALF / 64, NPOS / 64), 256, 0, stream>>>(
        FUB, W1T, pp1_b1, nullptr, P1, NPOS, HALF, HDIM);
    // H = P1 @ pp1_w2 + b2 + FUS
    mfma_gemm<64, 64, 32, 32, 0, true, false, true><<<dim3(HDIM / 64, NPOS / 64), 256, 0, stream>>>(
        P1, W2T, pp1_b2, FUF, Hh, NPOS, HDIM, HALF);
    // OUT = scatter(H @ pp2_w + pp2_b)
    mfma_gemm<128, 128, 64, 64, 0, false, true, false><<<dim3(12288 / 128, (NPOS + 127) / 128), 256, 0, stream>>>(
        Hh, PP2T, pp2_b, nullptr, OUT, NPOS, 12288, HDIM);

    // loss_cl = 0.0f
    hipMemsetAsync((float*)d_out + (out_size - 1), 0, 4, stream);
}

// Round 3
// 248.790 us; speedup vs baseline: 3.8962x; 1.3446x over previous
//
#include <hip/hip_runtime.h>

#define HDIM 512
#define HALF 256
#define NRELS 12
#define NBASES 8
#define NLAYERS 12
#define NBLOCKS 2
#define NHEADS 8
#define NENTS 50000
#define TXTD 768
#define BATCH 32
#define ELEN 50
#define SLEN 128
#define NPOS (BATCH * ELEN)   // 1600

typedef unsigned short u16;
typedef __attribute__((ext_vector_type(8))) __bf16 bf16x8;
typedef __attribute__((ext_vector_type(4))) float f32x4;

__device__ __forceinline__ u16 f2bf(float f) {
    unsigned int u = __float_as_uint(f);
    unsigned int r = (u + 0x7FFFu + ((u >> 16) & 1u)) >> 16;
    return (u16)r;
}
__device__ __forceinline__ float bf2f(u16 v) {
    return __uint_as_float(((unsigned int)v) << 16);
}

#define ASYNC_COPY16(g, l)                                                              \
    __builtin_amdgcn_global_load_lds((const __attribute__((address_space(1))) void*)(g), \
                                     (__attribute__((address_space(3))) unsigned int*)(l), 16, 0, 0)

// ---------------------------------------------------------------------------
// 0) One init kernel replacing all memsets; also zeroes the loss scalar.
// ---------------------------------------------------------------------------
__global__ void init_kernel(float* __restrict__ agg, float* __restrict__ cnt,
                            int* __restrict__ map, int* __restrict__ nuniq,
                            float* __restrict__ zb, float* __restrict__ out_last) {
    int tid = blockIdx.x * blockDim.x + threadIdx.x;
    int nt = gridDim.x * blockDim.x;
    float4 z4 = {0.f, 0.f, 0.f, 0.f};
    for (int i = tid; i < (NPOS * NRELS * HALF) / 4; i += nt) ((float4*)agg)[i] = z4;
    for (int i = tid; i < (NPOS * NRELS) / 4; i += nt) ((float4*)cnt)[i] = z4;
    int4 m4 = {-1, -1, -1, -1};
    for (int i = tid; i < NENTS / 4; i += nt) ((int4*)map)[i] = m4;
    for (int i = tid; i < 1536; i += nt) zb[i] = 0.f;
    if (tid == 0) { *nuniq = 0; *out_last = 0.f; }
}

// ---------------------------------------------------------------------------
// 1) Dedupe entity ids -> compact unique list + map[NENTS] (-1 = unused)
// ---------------------------------------------------------------------------
__global__ void dedup_kernel(const int* __restrict__ eid, int* __restrict__ map,
                             int* __restrict__ uniq, int* __restrict__ nuniq) {
    int i = blockIdx.x * blockDim.x + threadIdx.x;
    if (i >= NPOS) return;
    int n = eid[i];
    int old = atomicCAS(&map[n], -1, -2);
    if (old == -1) {
        int idx = atomicAdd(nuniq, 1);
        uniq[idx] = n;
        __threadfence();
        map[n] = idx;
    }
}

// ---------------------------------------------------------------------------
// 2) Edge scan: ballot-select edges whose dst is a needed node
// ---------------------------------------------------------------------------
__global__ void edge_scatter_kernel(const int* __restrict__ ei, const int* __restrict__ et,
                                    const int* __restrict__ map, const float* __restrict__ x,
                                    float* __restrict__ agg, float* __restrict__ cnt, int E) {
    const int* __restrict__ srcA = ei;
    const int* __restrict__ dstA = ei + E;
    int lane = threadIdx.x & 63;
    int wave = (blockIdx.x * blockDim.x + threadIdx.x) >> 6;
    int nwaves = (gridDim.x * blockDim.x) >> 6;
    for (int base = wave * 64; base < E; base += nwaves * 64) {
        int e = base + lane;
        int c = -1, rel = 0, src = 0;
        if (e < E) {
            int d = dstA[e];
            c = map[d];
            if (c >= 0) { rel = et[e]; src = srcA[e]; }
        }
        unsigned long long m = __ballot(c >= 0);
        while (m) {
            int bit = __builtin_ctzll(m);
            m &= m - 1;
            int cc = __shfl(c, bit);
            int rr = __shfl(rel, bit);
            int ss = __shfl(src, bit);
            float4 v = ((const float4*)(x + (size_t)ss * HALF))[lane];
            float* dest = agg + ((size_t)cc * NRELS + rr) * HALF + lane * 4;
            atomicAdd(dest + 0, v.x);
            atomicAdd(dest + 1, v.y);
            atomicAdd(dest + 2, v.z);
            atomicAdd(dest + 3, v.w);
            if (lane == 0) atomicAdd(&cnt[cc * NRELS + rr], 1.0f);
        }
    }
}

// ---------------------------------------------------------------------------
// 3) Build MBX[u, 2304] bf16
// ---------------------------------------------------------------------------
__global__ void build_mbx_kernel(const float* __restrict__ agg, const float* __restrict__ cnt,
                                 const int* __restrict__ uniq, const int* __restrict__ nuniq,
                                 const float* __restrict__ comp, const float* __restrict__ x,
                                 u16* __restrict__ MBX) {
    int u = blockIdx.x;
    int i = threadIdx.x;  // 256 threads
    __shared__ float sc[NRELS * NBASES];
    if (i < NRELS * NBASES) sc[i] = comp[i];
    __syncthreads();
    u16* row = MBX + (size_t)u * (NBASES * HALF + HALF);
    int nu = *nuniq;
    if (u >= nu) {
        for (int b = 0; b < NBASES + 1; ++b) row[b * HALF + i] = 0;
        return;
    }
    float mr[NRELS];
    for (int r = 0; r < NRELS; ++r) {
        float c = cnt[u * NRELS + r];
        float inv = 1.f / fmaxf(c, 1.f);
        mr[r] = agg[((size_t)u * NRELS + r) * HALF + i] * inv;
    }
    #pragma unroll
    for (int b = 0; b < NBASES; ++b) {
        float a = 0.f;
        #pragma unroll
        for (int r = 0; r < NRELS; ++r) a += sc[r * NBASES + b] * mr[r];
        row[b * HALF + i] = f2bf(a);
    }
    row[NBASES * HALF + i] = f2bf(x[(size_t)uniq[u] * HALF + i]);
}

// ---------------------------------------------------------------------------
// 4) Gather text/image raw features for unique nodes -> bf16 (float4 vec)
// ---------------------------------------------------------------------------
__global__ void gather_txim_kernel(const int* __restrict__ uniq, const int* __restrict__ nuniq,
                                   const float* __restrict__ txi, const float* __restrict__ imi,
                                   u16* __restrict__ TXIN, u16* __restrict__ IMIN) {
    int u = blockIdx.x;
    int t = threadIdx.x;
    int nu = *nuniq;
    if (t >= TXTD / 4) return;  // 192 lanes used
    if (u >= nu) {
        ushort4 z = {0, 0, 0, 0};
        ((ushort4*)(TXIN + (size_t)u * TXTD))[t] = z;
        ((ushort4*)(IMIN + (size_t)u * TXTD))[t] = z;
        return;
    }
    int n = uniq[u];
    float4 v = ((const float4*)(txi + (size_t)n * TXTD))[t];
    ushort4 o;
    o.x = f2bf(v.x); o.y = f2bf(v.y); o.z = f2bf(v.z); o.w = f2bf(v.w);
    ((ushort4*)(TXIN + (size_t)u * TXTD))[t] = o;
    v = ((const float4*)(imi + (size_t)n * TXTD))[t];
    o.x = f2bf(v.x); o.y = f2bf(v.y); o.z = f2bf(v.z); o.w = f2bf(v.w);
    ((ushort4*)(IMIN + (size_t)u * TXTD))[t] = o;
}

// ---------------------------------------------------------------------------
// 5) q[b] = mean_s(token_embeds[b]) @ cq_w + cq_b  -> bf16 QB; ct[z][b] fused
// ---------------------------------------------------------------------------
__global__ void qct_kernel(const float* __restrict__ tok, const float* __restrict__ cq_w,
                           const float* __restrict__ cq_b, const float* __restrict__ kgb,
                           const float* __restrict__ imb, const float* __restrict__ txb,
                           u16* __restrict__ qbf, float* __restrict__ CT) {
    int b = blockIdx.x;
    int t = threadIdx.x;  // 256
    __shared__ float mv[HDIM];
    for (int col = t; col < HDIM; col += 256) {
        float s = 0.f;
        for (int si = 0; si < SLEN; ++si) s += tok[((size_t)b * SLEN + si) * HDIM + col];
        mv[col] = s * (1.0f / SLEN);
    }
    __syncthreads();
    float a0 = cq_b[t];
    for (int i = 0; i < HDIM; ++i) a0 += mv[i] * cq_w[(size_t)i * HDIM + t];
    qbf[(size_t)b * HDIM + t] = f2bf(a0);
    float a1 = cq_b[t + 256];
    for (int i = 0; i < HDIM; ++i) a1 += mv[i] * cq_w[(size_t)i * HDIM + t + 256];
    qbf[(size_t)b * HDIM + t + 256] = f2bf(a1);
    __shared__ float red[256];
    // z = 0 (kg)
    red[t] = a0 * kgb[t] + a1 * kgb[t + 256];
    __syncthreads();
    for (int s = 128; s; s >>= 1) { if (t < s) red[t] += red[t + s]; __syncthreads(); }
    if (t == 0) CT[0 * BATCH + b] = red[0];
    __syncthreads();
    // z = 1 (im)
    red[t] = a0 * imb[t] + a1 * imb[t + 256];
    __syncthreads();
    for (int s = 128; s; s >>= 1) { if (t < s) red[t] += red[t + s]; __syncthreads(); }
    if (t == 0) CT[1 * BATCH + b] = red[0];
    __syncthreads();
    // z = 2 (tx)
    red[t] = a0 * txb[t] + a1 * txb[t + 256];
    __syncthreads();
    for (int s = 128; s; s >>= 1) { if (t < s) red[t] += red[t + s]; __syncthreads(); }
    if (t == 0) CT[2 * BATCH + b] = red[0];
}

// ---------------------------------------------------------------------------
// 6) fusion: softmax scores -> fused (qp stride 1536: [b][z*512+e])
// ---------------------------------------------------------------------------
__global__ void fusion_kernel(const int* __restrict__ eid, const int* __restrict__ map,
                              const u16* __restrict__ KGU, const u16* __restrict__ IMU,
                              const u16* __restrict__ TXU, const float* __restrict__ qp,
                              const float* __restrict__ ct, u16* __restrict__ fusedb,
                              float* __restrict__ fusedf) {
    int bl = blockIdx.x;
    int t = threadIdx.x;  // 256
    int b = bl / ELEN;
    int u = map[eid[bl]];
    const u16* kg = KGU + (size_t)u * HDIM;
    const u16* im = IMU + (size_t)u * HDIM;
    const u16* tx = TXU + (size_t)u * HDIM;
    const float* qkg = qp + (size_t)b * 1536 + 0;
    const float* qim = qp + (size_t)b * 1536 + 512;
    const float* qtx = qp + (size_t)b * 1536 + 1024;
    float pkg = 0.f, pim = 0.f, ptx = 0.f;
    for (int e = t; e < HDIM; e += 256) {
        pkg += bf2f(kg[e]) * qkg[e];
        pim += bf2f(im[e]) * qim[e];
        ptx += bf2f(tx[e]) * qtx[e];
    }
    __shared__ float s0[256], s1[256], s2[256];
    s0[t] = pkg; s1[t] = pim; s2[t] = ptx;
    __syncthreads();
    for (int s = 128; s > 0; s >>= 1) {
        if (t < s) { s0[t] += s0[t + s]; s1[t] += s1[t + s]; s2[t] += s2[t + s]; }
        __syncthreads();
    }
    __shared__ float w[3];
    if (t == 0) {
        float a = s0[0] + ct[0 * BATCH + b];
        float c1 = s1[0] + ct[1 * BATCH + b];
        float c2 = s2[0] + ct[2 * BATCH + b];
        float mx = fmaxf(a, fmaxf(c1, c2));
        float ea = __expf(a - mx), eb = __expf(c1 - mx), ec = __expf(c2 - mx);
        float inv = 1.f / (ea + eb + ec);
        w[0] = ea * inv; w[1] = eb * inv; w[2] = ec * inv;
    }
    __syncthreads();
    float w0 = w[0], w1 = w[1], w2 = w[2];
    for (int e = t; e < HDIM; e += 256) {
        float v = w0 * bf2f(kg[e]) + w1 * bf2f(im[e]) + w2 * bf2f(tx[e]);
        fusedf[(size_t)bl * HDIM + e] = v;
        fusedb[(size_t)bl * HDIM + e] = f2bf(v);
    }
}

// ---------------------------------------------------------------------------
// 7) ONE weight-prep kernel: 8 transposes + 3 converts, compile-time table.
//    op<8: fp32 [K,N] -> bf16 [N][koff+k] (32x32 tiles)
//    op>=8: straight fp32 -> bf16 convert (1024 elems/tile)
// ---------------------------------------------------------------------------
struct PrepArgs {
    const float* src[11];
    u16* dst[11];
};
__global__ __launch_bounds__(256) void prep_kernel(PrepArgs a) {
    // op:            0:basis 1:root 2:kgproj 3:txproj 4:improj 5:w1 6:w2 7:pp2 | 8,9,10: score convs
    constexpr int KK[8]   = {2048, 256, 256, 768, 768, 512, 256, 512};
    constexpr int NN[8]   = {256, 256, 512, 512, 512, 256, 512, 12288};
    constexpr int LDT[8]  = {2304, 2304, 256, 768, 768, 512, 256, 512};
    constexpr int KOFF[8] = {0, 2048, 0, 0, 0, 0, 0, 0};
    constexpr int BASE[12] = {0, 512, 576, 704, 1088, 1472, 1600, 1728, 7872, 8128, 8384, 8640};
    __shared__ u16 tb[32][33];
    int bid = blockIdx.x;
    int op = 0;
    #pragma unroll
    for (int i = 1; i < 11; ++i)
        if (bid >= BASE[i]) op = i;
    int idx = bid - BASE[op];
    if (op < 8) {
        int Kv = 0, Nv = 0, ldt = 0, koff = 0;
        #pragma unroll
        for (int i = 0; i < 8; ++i)
            if (op == i) { Kv = KK[i]; Nv = NN[i]; ldt = LDT[i]; koff = KOFF[i]; }
        (void)Kv;
        int ncols = Nv / 32;
        int n0 = (idx % ncols) * 32, k0 = (idx / ncols) * 32;
        const float* W = a.src[op];
        u16* WT = a.dst[op];
        int tx = threadIdx.x & 31, ty = threadIdx.x >> 5;  // 32 x 8
        #pragma unroll
        for (int i = ty; i < 32; i += 8)
            tb[i][tx] = f2bf(W[(size_t)(k0 + i) * Nv + n0 + tx]);
        __syncthreads();
        #pragma unroll
        for (int i = ty; i < 32; i += 8)
            WT[(size_t)(n0 + i) * ldt + koff + k0 + tx] = tb[tx][i];
    } else {
        int e = idx * 1024 + threadIdx.x * 4;
        float4 v = *(const float4*)(a.src[op] + e);
        ushort4 o;
        o.x = f2bf(v.x); o.y = f2bf(v.y); o.z = f2bf(v.z); o.w = f2bf(v.w);
        *(ushort4*)(a.dst[op] + e) = o;
    }
}

// ---------------------------------------------------------------------------
// MFMA bf16 GEMM body: C[M,N] = A[M,K](bf16) @ BT[N,K](bf16)^T + bias
// ---------------------------------------------------------------------------
template <int BM, int BN, int WM, int WN, int ACT, bool RES, bool SCATTER, bool OUTBF>
__device__ __forceinline__ void gemm_body(const u16* __restrict__ A, const u16* __restrict__ BT,
                                          const float* __restrict__ bias, const float* __restrict__ res,
                                          void* __restrict__ Cout, int M, int N, int K,
                                          int bx, int by) {
    constexpr int MF = WM / 16, NF = WN / 16;
    constexpr int NWC = BN / WN;
    __shared__ u16 ldsA[BM][64];
    __shared__ u16 ldsB[BN][64];
    const int tid = threadIdx.x;
    const int lane = tid & 63;
    const int wv = tid >> 6;
    const int m0 = by * BM;
    const int n0 = bx * BN;
    const int wr = wv / NWC, wc = wv % NWC;
    const int srow = lane >> 3;
    const int sslot = lane & 7;

    f32x4 acc[MF][NF];
    #pragma unroll
    for (int i = 0; i < MF; ++i)
        #pragma unroll
        for (int j = 0; j < NF; ++j)
            #pragma unroll
            for (int r = 0; r < 4; ++r) acc[i][j][r] = 0.f;

    for (int k0 = 0; k0 < K; k0 += 64) {
        #pragma unroll
        for (int i = 0; i < BM / 32; ++i) {
            int R = wv * (BM / 4) + i * 8 + srow;
            int gm = m0 + R;
            gm = gm < M ? gm : M - 1;
            int s = sslot ^ (R & 7);
            ASYNC_COPY16(A + (size_t)gm * K + k0 + s * 8, &ldsA[wv * (BM / 4) + i * 8][0]);
        }
        #pragma unroll
        for (int i = 0; i < BN / 32; ++i) {
            int R = wv * (BN / 4) + i * 8 + srow;
            int s = sslot ^ (R & 7);
            ASYNC_COPY16(BT + (size_t)(n0 + R) * K + k0 + s * 8, &ldsB[wv * (BN / 4) + i * 8][0]);
        }
        __syncthreads();
        #pragma unroll
        for (int ks = 0; ks < 2; ++ks) {
            bf16x8 af[MF], bf[NF];
            int kg = ks * 4 + (lane >> 4);
            int rl = lane & 15;
            #pragma unroll
            for (int i = 0; i < MF; ++i) {
                int row = wr * WM + i * 16 + rl;
                af[i] = *(const bf16x8*)&ldsA[row][(kg ^ (row & 7)) * 8];
            }
            #pragma unroll
            for (int j = 0; j < NF; ++j) {
                int row = wc * WN + j * 16 + rl;
                bf[j] = *(const bf16x8*)&ldsB[row][(kg ^ (row & 7)) * 8];
            }
            #pragma unroll
            for (int i = 0; i < MF; ++i)
                #pragma unroll
                for (int j = 0; j < NF; ++j)
                    acc[i][j] = __builtin_amdgcn_mfma_f32_16x16x32_bf16(af[i], bf[j], acc[i][j], 0, 0, 0);
        }
        __syncthreads();
    }

    const int rl = lane & 15, rg = lane >> 4;
    #pragma unroll
    for (int i = 0; i < MF; ++i) {
        #pragma unroll
        for (int j = 0; j < NF; ++j) {
            int col = n0 + wc * WN + j * 16 + rl;
            float bv = bias[col];
            #pragma unroll
            for (int r = 0; r < 4; ++r) {
                int row = m0 + wr * WM + i * 16 + rg * 4 + r;
                if (row >= M) continue;
                float x = acc[i][j][r] + bv;
                if (ACT == 1) x = fmaxf(x, 0.f);
                if (RES) x += res[(size_t)row * N + col];
                if (SCATTER) {
                    int layer = col >> 10, blk = (col >> 9) & 1, head = (col >> 6) & 7, hd = col & 63;
                    int bb = row / ELEN, ll = row - bb * ELEN;
                    size_t oi = (((((size_t)layer * NBLOCKS + blk) * BATCH + bb) * NHEADS + head) * ELEN + ll) * 64 + hd;
                    ((float*)Cout)[oi] = x;
                } else if (OUTBF) {
                    ((u16*)Cout)[(size_t)row * N + col] = f2bf(x);
                } else {
                    ((float*)Cout)[(size_t)row * N + col] = x;
                }
            }
        }
    }
}

template <int BM, int BN, int WM, int WN, int ACT, bool RES, bool SCATTER, bool OUTBF>
__global__ __launch_bounds__(256)
void mfma_gemm(const u16* __restrict__ A, const u16* __restrict__ BT,
               const float* __restrict__ bias, const float* __restrict__ res,
               void* __restrict__ Cout, int M, int N, int K) {
    gemm_body<BM, BN, WM, WN, ACT, RES, SCATTER, OUTBF>(A, BT, bias, res, Cout, M, N, K,
                                                        blockIdx.x, blockIdx.y);
}

// batched 3-way projection: z selects (A, BT, bias, C, K); all [1600 x 512] bf16 out
struct Proj3Args {
    const u16* A[3];
    const u16* B[3];
    const float* bias[3];
    u16* C[3];
    int K[3];
};
__global__ __launch_bounds__(256) void proj3_kernel(Proj3Args a) {
    int z = blockIdx.z;
    gemm_body<64, 64, 32, 32, 0, false, false, true>(a.A[z], a.B[z], a.bias[z], nullptr,
                                                     a.C[z], NPOS, HDIM, a.K[z],
                                                     blockIdx.x, blockIdx.y);
}

// ---------------------------------------------------------------------------
extern "C" void kernel_launch(void* const* d_in, const int* in_sizes, int n_in,
                              void* d_out, int out_size, void* d_ws, size_t ws_size,
                              hipStream_t stream) {
    const int* entity_ids = (const int*)d_in[0];
    const float* token_embeds = (const float*)d_in[1];
    const int* edge_index = (const int*)d_in[2];
    const int* edge_type = (const int*)d_in[3];
    const float* node_embeds = (const float*)d_in[4];
    const float* rgcn_basis = (const float*)d_in[5];
    const float* rgcn_comp = (const float*)d_in[6];
    const float* rgcn_root = (const float*)d_in[7];
    const float* rgcn_bias = (const float*)d_in[8];
    const float* kg_proj_w = (const float*)d_in[9];
    const float* kg_proj_b = (const float*)d_in[10];
    const float* text_proj_w = (const float*)d_in[11];
    const float* text_proj_b = (const float*)d_in[12];
    const float* image_proj_w = (const float*)d_in[13];
    const float* image_proj_b = (const float*)d_in[14];
    const float* cq_w = (const float*)d_in[15];
    const float* cq_b = (const float*)d_in[16];
    const float* kgk_w = (const float*)d_in[17];
    const float* imk_w = (const float*)d_in[19];
    const float* txk_w = (const float*)d_in[21];
    const float* pp1_w1 = (const float*)d_in[23];
    const float* pp1_b1 = (const float*)d_in[24];
    const float* pp1_w2 = (const float*)d_in[25];
    const float* pp1_b2 = (const float*)d_in[26];
    const float* pp2_w = (const float*)d_in[27];
    const float* pp2_b = (const float*)d_in[28];
    const float* text_init = (const float*)d_in[29];
    const float* image_init = (const float*)d_in[30];

    const int E = in_sizes[3];  // 500000

    size_t off = 0;
    auto alloc = [&](size_t bytes) { size_t o = off; off += (bytes + 255) & ~(size_t)255; return o; };
    char* ws = (char*)d_ws;
    size_t map_o  = alloc((size_t)NENTS * 4);
    size_t nun_o  = alloc(4);
    size_t unq_o  = alloc((size_t)NPOS * 4);
    size_t cnt_o  = alloc((size_t)NPOS * NRELS * 4);
    size_t agg_o  = alloc((size_t)NPOS * NRELS * HALF * 4);   // 19.66MB; PP2T aliases after build_mbx
    size_t mbx_o  = alloc((size_t)NPOS * 2304 * 2);
    size_t bbt_o  = alloc((size_t)HALF * 2304 * 2);
    size_t rg_o   = alloc((size_t)NPOS * HALF * 2);
    size_t kgt_o  = alloc((size_t)HDIM * HALF * 2);
    size_t kgu_o  = alloc((size_t)NPOS * HDIM * 2);
    size_t txin_o = alloc((size_t)NPOS * TXTD * 2);
    size_t imin_o = alloc((size_t)NPOS * TXTD * 2);
    size_t txt_o  = alloc((size_t)HDIM * TXTD * 2);
    size_t imt_o  = alloc((size_t)HDIM * TXTD * 2);
    size_t txu_o  = alloc((size_t)NPOS * HDIM * 2);
    size_t imu_o  = alloc((size_t)NPOS * HDIM * 2);
    size_t qb_o   = alloc((size_t)BATCH * HDIM * 2);
    size_t kgw_o  = alloc((size_t)3 * HDIM * HDIM * 2);       // stacked kg/im/tx score weights
    size_t qp_o   = alloc((size_t)BATCH * 3 * HDIM * 4);
    size_t ct_o   = alloc((size_t)3 * BATCH * 4);
    size_t zb_o   = alloc((size_t)1536 * 4);
    size_t fub_o  = alloc((size_t)NPOS * HDIM * 2);
    size_t fuf_o  = alloc((size_t)NPOS * HDIM * 4);
    size_t p1_o   = alloc((size_t)NPOS * HALF * 2);
    size_t w1t_o  = alloc((size_t)HALF * HDIM * 2);
    size_t w2t_o  = alloc((size_t)HDIM * HALF * 2);
    size_t h_o    = alloc((size_t)NPOS * HDIM * 2);
    if (off > ws_size) return;

    int* map = (int*)(ws + map_o);
    int* nuniq = (int*)(ws + nun_o);
    int* uniq = (int*)(ws + unq_o);
    float* cnt = (float*)(ws + cnt_o);
    float* agg = (float*)(ws + agg_o);
    u16* MBX = (u16*)(ws + mbx_o);
    u16* BBT = (u16*)(ws + bbt_o);
    u16* RG  = (u16*)(ws + rg_o);
    u16* KGT = (u16*)(ws + kgt_o);
    u16* KGU = (u16*)(ws + kgu_o);
    u16* TXIN = (u16*)(ws + txin_o);
    u16* IMIN = (u16*)(ws + imin_o);
    u16* TXT = (u16*)(ws + txt_o);
    u16* IMT = (u16*)(ws + imt_o);
    u16* TXU = (u16*)(ws + txu_o);
    u16* IMU = (u16*)(ws + imu_o);
    u16* QB  = (u16*)(ws + qb_o);
    u16* KGW = (u16*)(ws + kgw_o);
    float* QP  = (float*)(ws + qp_o);
    float* CT  = (float*)(ws + ct_o);
    float* ZB  = (float*)(ws + zb_o);
    u16* FUB = (u16*)(ws + fub_o);
    float* FUF = (float*)(ws + fuf_o);
    u16* P1  = (u16*)(ws + p1_o);
    u16* W1T = (u16*)(ws + w1t_o);
    u16* W2T = (u16*)(ws + w2t_o);
    u16* Hh  = (u16*)(ws + h_o);
    u16* PP2T = (u16*)(ws + agg_o);  // alias: agg dead after build_mbx
    float* OUT = (float*)d_out;

    // 1) init (replaces all memsets; also writes loss scalar)
    init_kernel<<<1024, 256, 0, stream>>>(agg, cnt, map, nuniq, ZB, OUT + (out_size - 1));
    // 2) dedup
    dedup_kernel<<<(NPOS + 255) / 256, 256, 0, stream>>>(entity_ids, map, uniq, nuniq);
    // 3) edge scatter
    edge_scatter_kernel<<<1024, 256, 0, stream>>>(edge_index, edge_type, map, node_embeds, agg, cnt, E);
    // 4) build MBX (consumes agg)
    build_mbx_kernel<<<NPOS, 256, 0, stream>>>(agg, cnt, uniq, nuniq, rgcn_comp, node_embeds, MBX);
    // 5) weight prep (PP2T overwrites agg region — must be after build_mbx)
    PrepArgs pa;
    pa.src[0] = rgcn_basis;  pa.dst[0] = BBT;
    pa.src[1] = rgcn_root;   pa.dst[1] = BBT;
    pa.src[2] = kg_proj_w;   pa.dst[2] = KGT;
    pa.src[3] = text_proj_w; pa.dst[3] = TXT;
    pa.src[4] = image_proj_w; pa.dst[4] = IMT;
    pa.src[5] = pp1_w1;      pa.dst[5] = W1T;
    pa.src[6] = pp1_w2;      pa.dst[6] = W2T;
    pa.src[7] = pp2_w;       pa.dst[7] = PP2T;
    pa.src[8] = kgk_w;       pa.dst[8] = KGW;
    pa.src[9] = imk_w;       pa.dst[9] = KGW + (size_t)HDIM * HDIM;
    pa.src[10] = txk_w;      pa.dst[10] = KGW + (size_t)2 * HDIM * HDIM;
    prep_kernel<<<8640, 256, 0, stream>>>(pa);
    // 6) gather text/image rows
    gather_txim_kernel<<<NPOS, 256, 0, stream>>>(uniq, nuniq, text_init, image_init, TXIN, IMIN);
    // 7) q + ct fused
    qct_kernel<<<BATCH, 256, 0, stream>>>(token_embeds, cq_w, cq_b, (const float*)d_in[18],
                                          (const float*)d_in[20], (const float*)d_in[22], QB, CT);
    // 8) QP = QB @ [KGW;IMW;TXW]^T  (one GEMM, N=1536)
    mfma_gemm<64, 64, 32, 32, 0, false, false, false><<<dim3(24, 1), 256, 0, stream>>>(
        QB, KGW, ZB, nullptr, QP, BATCH, 1536, HDIM);
    // 9) RG = MBX @ BBT^T + rgcn_bias
    mfma_gemm<64, 64, 32, 32, 0, false, false, true><<<dim3(HALF / 64, NPOS / 64), 256, 0, stream>>>(
        MBX, BBT, rgcn_bias, nullptr, RG, NPOS, HALF, 2304);
    // 10) KGU / TXU / IMU batched
    Proj3Args p3;
    p3.A[0] = RG;   p3.B[0] = KGT; p3.bias[0] = kg_proj_b;    p3.C[0] = KGU; p3.K[0] = HALF;
    p3.A[1] = TXIN; p3.B[1] = TXT; p3.bias[1] = text_proj_b;  p3.C[1] = TXU; p3.K[1] = TXTD;
    p3.A[2] = IMIN; p3.B[2] = IMT; p3.bias[2] = image_proj_b; p3.C[2] = IMU; p3.K[2] = TXTD;
    proj3_kernel<<<dim3(HDIM / 64, NPOS / 64, 3), 256, 0, stream>>>(p3);
    // 11) fusion
    fusion_kernel<<<NPOS, 256, 0, stream>>>(entity_ids, map, KGU, IMU, TXU, QP, CT, FUB, FUF);
    // 12) P1 = relu(FUS @ pp1_w1 + b1)
    mfma_gemm<64, 64, 32, 32, 1, false, false, true><<<dim3(HALF / 64, NPOS / 64), 256, 0, stream>>>(
        FUB, W1T, pp1_b1, nullptr, P1, NPOS, HALF, HDIM);
    // 13) H = P1 @ pp1_w2 + b2 + FUS
    mfma_gemm<64, 64, 32, 32, 0, true, false, true><<<dim3(HDIM / 64, NPOS / 64), 256, 0, stream>>>(
        P1, W2T, pp1_b2, FUF, Hh, NPOS, HDIM, HALF);
    // 14) OUT = scatter(H @ pp2_w + pp2_b)
    mfma_gemm<128, 128, 64, 64, 0, false, true, false><<<dim3(12288 / 128, (NPOS + 127) / 128), 256, 0, stream>>>(
        Hh, PP2T, pp2_b, nullptr, OUT, NPOS, 12288, HDIM);
}